// Round 6
// baseline (184.843 us; speedup 1.0000x reference)
//
#include <hip/hip_runtime.h>
#include <stdint.h>

// Problem constants: B=2048, C=200, F=32, H=256. All tensors fp32 in/out.
// M = B*C = 409600 rows of 32 features, contiguous in x.
#define M_ROWS 409600
#define B_CNT  2048
#define C_CNT  200
#define N_TILES (M_ROWS / 64)    // 6400 tiles of 64 rows
#define GRID_MLP 512             // persistent blocks: 2 per CU
#define NW      8                // waves per block (512 threads)

typedef __attribute__((ext_vector_type(8))) short bf16x8;   // 8 bf16 = 4 VGPRs
typedef __attribute__((ext_vector_type(4))) float f32x4;

// round-to-nearest-even f32 -> bf16 bits (scalar path, prep kernel)
__device__ __forceinline__ ushort f2bf(float f) {
    uint32_t u = __float_as_uint(f);
    u += 0x7fffu + ((u >> 16) & 1u);
    return (ushort)(u >> 16);
}

// packed RNE f32x2 -> bf16x2 (single HW instruction)
__device__ __forceinline__ uint32_t cvtpk_bf16(float lo, float hi) {
    uint32_t r;
    asm("v_cvt_pk_bf16_f32 %0, %1, %2" : "=v"(r) : "v"(lo), "v"(hi));
    return r;
}

__device__ __forceinline__ f32x4 mfma16(bf16x8 a, bf16x8 b, f32x4 c) {
    return __builtin_amdgcn_mfma_f32_16x16x32_bf16(a, b, c, 0, 0, 0);
}

__device__ __forceinline__ bf16x8 pack8(float4 a, float4 b) {
    bf16x8 r;
    r[0] = (short)f2bf(a.x); r[1] = (short)f2bf(a.y);
    r[2] = (short)f2bf(a.z); r[3] = (short)f2bf(a.w);
    r[4] = (short)f2bf(b.x); r[5] = (short)f2bf(b.y);
    r[6] = (short)f2bf(b.z); r[7] = (short)f2bf(b.w);
    return r;
}

// ---------------------------------------------------------------------------
// Prep kernel (unchanged, measured-good):
//   blocks [0,2048):   one coalesced pass over the x row: bf16 copy (xb16),
//                      sinflow/iinflow, fused epilogue operand
//                      epi[gm] = {S, P, Q, 0}:
//                        P = S + sinflow - outflow*S,  Q = I + iinflow - outflow*I
//   blocks [2048,2304): W2^T -> bf16
//   blocks [2304,2336): W1^T -> bf16
// ---------------------------------------------------------------------------
__global__ __launch_bounds__(256) void prep_kernel(
    const float* __restrict__ x, const float* __restrict__ T,
    const float* __restrict__ W1, const float* __restrict__ W2,
    ushort* __restrict__ xb16, float4* __restrict__ epi,
    ushort* __restrict__ W1t, ushort* __restrict__ W2t, int do_xb) {
    int blk = blockIdx.x, t = threadIdx.x;
    if (blk < B_CNT) {
        __shared__ float Sr[C_CNT], Ir[C_CNT];
        const float4* xr = (const float4*)(x + (size_t)blk * 6400);  // 1600 f4
        ushort4* xw = (ushort4*)(xb16 + (size_t)blk * 6400);
#pragma unroll
        for (int i = 0; i < 7; ++i) {
            int i4 = i * 256 + t;
            if (i4 < 1600) {
                float4 v = xr[i4];
                if (do_xb) {
                    ushort4 u;
                    u.x = f2bf(v.x); u.y = f2bf(v.y);
                    u.z = f2bf(v.z); u.w = f2bf(v.w);
                    xw[i4] = u;
                }
                if ((i4 & 7) == 0) {           // element i4*4 is feature 0 of c
                    int c = i4 >> 3;
                    Sr[c] = v.x; Ir[c] = v.y;
                }
            }
        }
        __syncthreads();
        if (t < C_CNT) {
            float as = 0.f, ai = 0.f;
            for (int cp = 0; cp < C_CNT; ++cp) {
                float tv = T[cp * C_CNT + t];        // coalesced over t, L2-hot
                as = fmaf(Sr[cp], tv, as);
                ai = fmaf(Ir[cp], tv, ai);
            }
            float S = Sr[t], I = Ir[t];
            float of = 1.0f - T[t * C_CNT + t];
            float4 e;
            e.x = S;
            e.y = S + as - of * S;   // P
            e.z = I + ai - of * I;   // Q
            e.w = 0.f;
            epi[(size_t)blk * C_CNT + t] = e;
        }
    } else if (blk < B_CNT + 256) {
        int n = blk - B_CNT;                          // one n2 row per block
        W2t[n * 256 + t] = f2bf(W2[t * 256 + n]);     // write coalesced
    } else {
        int idx = (blk - B_CNT - 256) * 256 + t;      // 0..8191
        int n = idx >> 5, k = idx & 31;
        W1t[idx] = f2bf(W1[k * 256 + n]);
    }
}

// ---------------------------------------------------------------------------
// Persistent fused MLP kernel — 8 waves/block (512 thr), 32-column wave slices.
// Halves per-wave registers vs the 4-wave plan: a2r 64 + acc2 32 + bh 16
// + addressing ~ 125 regs -> launch_bounds(512,4) pins 128 -> 4 waves/SIMD
// (16 waves/CU with 2 blocks/CU) and no scratch spill.
// Same 1-barrier/tile software pipeline as r5:
//   aw load | GEMM1(t) [bx preloaded] | pack(t)->h1s[buf]
//   BARRIER | epilogue(t-1) [epi regs prefetched] | GEMM2(t) regs x LDS
//   | bx reload(t+1) (after the register peak) | epi prefetch(t) | GEMM3(t)
// ---------------------------------------------------------------------------
template <bool XB>
__global__ __launch_bounds__(512, 4) void mlp_kernel(
    const float* __restrict__ x,
    const ushort* __restrict__ xb16,
    const float* __restrict__ b1,
    const float* __restrict__ b2,
    const float* __restrict__ W3,
    const float* __restrict__ b3,
    const ushort* __restrict__ W1t,   // [256][32]  bf16, n1-major
    const ushort* __restrict__ W2t,   // [256][256] bf16, n2-major
    const float4* __restrict__ epi,   // {S, P, Q, 0} per row
    float* __restrict__ out) {
    constexpr int RS = 264;  // h1 row stride (ushorts): rows 16B-aligned
    __shared__ ushort h1s[2][64 * RS];       // 2 x 33792 B
    __shared__ float b1f[256], b2f[256], w3f[256];
    __shared__ float lamb2[2][NW][64];       // parity double buffer

    const int tid  = threadIdx.x;
    const int w    = tid >> 6;               // 0..7
    const int lane = tid & 63;
    const int L    = lane & 15;
    const int q    = lane >> 4;

    if (tid < 256) {
        b1f[tid] = b1[tid];
        b2f[tid] = b2[tid];
        w3f[tid] = W3[tid];
    }
    const float b3v = b3[0];

    // ---- register-resident W2t slice: 32 n2-rows x 256 k = 64 regs ----
    bf16x8 a2r[2][8];                 // [i2][kc]
#pragma unroll
    for (int i2 = 0; i2 < 2; ++i2)
#pragma unroll
        for (int kc = 0; kc < 8; ++kc)
            a2r[i2][kc] =
                *(const bf16x8*)(W2t + (32 * w + i2 * 16 + L) * 256 + kc * 32 + q * 8);

    // W1t fragment byte-offset (32-bit, SGPR base); laundered per iteration
    uint32_t w1off = (uint32_t)(((32 * w + L) * 32 + q * 8) * sizeof(ushort));

    // ---- prologue: preload bx (all 64 m-rows) for the first tile ----
    int tile = blockIdx.x;
    bf16x8 bx[4];
#pragma unroll
    for (int i = 0; i < 4; ++i) {
        if (XB) {
            bx[i] = *(const bf16x8*)(xb16 + (size_t)(tile * 64 + i * 16 + L) * 32 + q * 8);
        } else {
            const float4* xr =
                (const float4*)(x + (size_t)(tile * 64 + i * 16 + L) * 32 + q * 8);
            bx[i] = pack8(xr[0], xr[1]);
        }
    }

    float eS = 0.f, eP = 0.f, eQ = 0.f;  // prefetched epilogue operands
    int ptile = -1;      // tile whose epilogue is pending
    int buf = 0, wp = 0;

    __syncthreads();     // b1f/b2f/w3f visible

    for (; tile < N_TILES; tile += GRID_MLP) {
        // ---- aw: reload per tile (L1-hot 16KB); launder blocks LICM ----
        asm volatile("" : "+v"(w1off));
        const char* w1p = (const char*)W1t + w1off;
        bf16x8 aw[2];
#pragma unroll
        for (int i = 0; i < 2; ++i)
            aw[i] = *(const bf16x8*)(w1p + (size_t)i * 1024);  // 16 rows x 64B

        // ---- GEMM1 (K=32): 32 n1-cols x 64 m-rows per wave ----
        f32x4 acc1[2][4];
#pragma unroll
        for (int i1 = 0; i1 < 2; ++i1)
#pragma unroll
            for (int im = 0; im < 4; ++im)
                acc1[i1][im] = mfma16(aw[i1], bx[im], (f32x4){0.f, 0.f, 0.f, 0.f});

        // ---- pack h1 (bias+relu fp32, cvt_pk bf16) -> h1s[buf] ----
        // Safe pre-barrier: buf == buf(t-2); all waves passed barrier(t-1),
        // whose program order puts GEMM2(t-2) (last reader of buf) before it.
#pragma unroll
        for (int i1 = 0; i1 < 2; ++i1) {
            int n1b = 32 * w + i1 * 16 + q * 4;
            const float4 bv = *reinterpret_cast<const float4*>(&b1f[n1b]);
#pragma unroll
            for (int im = 0; im < 4; ++im) {
                int m = im * 16 + L;
                float v0 = fmaxf(acc1[i1][im][0] + bv.x, 0.f);
                float v1 = fmaxf(acc1[i1][im][1] + bv.y, 0.f);
                float v2 = fmaxf(acc1[i1][im][2] + bv.z, 0.f);
                float v3 = fmaxf(acc1[i1][im][3] + bv.w, 0.f);
                uint2 pk;
                pk.x = cvtpk_bf16(v0, v1);
                pk.y = cvtpk_bf16(v2, v3);
                *reinterpret_cast<uint2*>(&h1s[buf][m * RS + n1b]) = pk;
            }
        }

        __syncthreads();   // THE barrier: h1s[buf] ready; lamb2[wp^1] visible

        // ---- pipelined epilogue for tile t-1 (overlaps other waves' GEMM2)
        if (ptile >= 0 && tid < 64) {
            int gm = ptile * 64 + tid;
            float lam = b3v;
#pragma unroll
            for (int j = 0; j < NW; ++j) lam += lamb2[wp ^ 1][j][tid];
            float2 o;
            o.x = eP - lam * eS;
            o.y = eQ + lam * eS;
            ((float2*)out)[gm] = o;   // coalesced 8B store
        }

        // ---- GEMM2 (K=256, 8 k-chunks): A from registers, B from LDS ----
        f32x4 acc2[2][4];
#pragma unroll
        for (int i2 = 0; i2 < 2; ++i2)
#pragma unroll
            for (int im = 0; im < 4; ++im) acc2[i2][im] = (f32x4){0.f, 0.f, 0.f, 0.f};

#pragma unroll
        for (int kc = 0; kc < 8; ++kc) {
            bf16x8 bh[4];
#pragma unroll
            for (int im = 0; im < 4; ++im) {
                int m = im * 16 + L;
                bh[im] = *(const bf16x8*)(&h1s[buf][m * RS + kc * 32 + q * 8]);
            }
#pragma unroll
            for (int i2 = 0; i2 < 2; ++i2)
#pragma unroll
                for (int im = 0; im < 4; ++im)
                    acc2[i2][im] = mfma16(a2r[i2][kc], bh[im], acc2[i2][im]);
        }

        // ---- bx reload for next tile: AFTER the GEMM2 register peak ----
        {
            int tn = tile + GRID_MLP;
            if (tn >= N_TILES) tn = tile;   // harmless dummy reload on last iter
            const size_t mn0 = (size_t)tn * 64;
#pragma unroll
            for (int i = 0; i < 4; ++i) {
                if (XB) {
                    bx[i] = *(const bf16x8*)(xb16 + (mn0 + i * 16 + L) * 32 + q * 8);
                } else {
                    const float4* xr =
                        (const float4*)(x + (mn0 + i * 16 + L) * 32 + q * 8);
                    bx[i] = pack8(xr[0], xr[1]);
                }
            }
        }

        // ---- prefetch epilogue operands for THIS tile (consumed next iter)
        if (tid < 64) {
            float4 e = epi[(size_t)tile * 64 + tid];
            eS = e.x; eP = e.y; eQ = e.z;
        }

        // ---- GEMM3: lamb[m] partial over this wave's 32 n2 (fp32, exact) ----
        float part[4] = {0.f, 0.f, 0.f, 0.f};
#pragma unroll
        for (int i2 = 0; i2 < 2; ++i2) {
            int n2b = 32 * w + i2 * 16 + q * 4;
            const float4 b2v = *reinterpret_cast<const float4*>(&b2f[n2b]);
            const float4 w3v = *reinterpret_cast<const float4*>(&w3f[n2b]);
#pragma unroll
            for (int im = 0; im < 4; ++im) {
                float h0 = fmaxf(acc2[i2][im][0] + b2v.x, 0.f);
                float h1 = fmaxf(acc2[i2][im][1] + b2v.y, 0.f);
                float h2 = fmaxf(acc2[i2][im][2] + b2v.z, 0.f);
                float h3 = fmaxf(acc2[i2][im][3] + b2v.w, 0.f);
                part[im] = fmaf(h0, w3v.x, part[im]);
                part[im] = fmaf(h1, w3v.y, part[im]);
                part[im] = fmaf(h2, w3v.z, part[im]);
                part[im] = fmaf(h3, w3v.w, part[im]);
            }
        }

#pragma unroll
        for (int im = 0; im < 4; ++im) {
            float pp = part[im];
            pp += __shfl_xor(pp, 16);
            pp += __shfl_xor(pp, 32);
            if (q == 0) lamb2[wp][w][im * 16 + L] = pp;
        }
        // lamb2[wp] is consumed only after the NEXT barrier.

        ptile = tile;
        buf ^= 1;
        wp ^= 1;
    }

    // ---- drain: epilogue for the final tile ----
    __syncthreads();
    if (ptile >= 0 && tid < 64) {
        int gm = ptile * 64 + tid;
        float lam = b3v;
#pragma unroll
        for (int j = 0; j < NW; ++j) lam += lamb2[wp ^ 1][j][tid];
        float2 o;
        o.x = eP - lam * eS;
        o.y = eQ + lam * eS;
        ((float2*)out)[gm] = o;
    }
}

// ---------------------------------------------------------------------------
extern "C" void kernel_launch(void* const* d_in, const int* in_sizes, int n_in,
                              void* d_out, int out_size, void* d_ws, size_t ws_size,
                              hipStream_t stream) {
    const float* x  = (const float*)d_in[0];
    const float* T  = (const float*)d_in[1];
    const float* W1 = (const float*)d_in[2];
    const float* b1 = (const float*)d_in[3];
    const float* W2 = (const float*)d_in[4];
    const float* b2 = (const float*)d_in[5];
    const float* W3 = (const float*)d_in[6];
    const float* b3 = (const float*)d_in[7];

    // ws layout: [xb16 (opt, 26.2 MB)] epi (6.55 MB) W1t (16KB) W2t (128KB)
    const size_t xb_bytes = (size_t)M_ROWS * 32 * 2;
    const size_t epi_b    = (size_t)M_ROWS * 16;
    const size_t small    = epi_b + 8192 * 2 + 65536 * 2;
    const int    do_xb    = (ws_size >= xb_bytes + small) ? 1 : 0;

    char* ws = (char*)d_ws;
    ushort* xb16 = (ushort*)ws;
    char* base = ws + (do_xb ? xb_bytes : 0);
    float4* epi  = (float4*)(base);
    ushort* W1t  = (ushort*)(base + epi_b);
    ushort* W2t  = (ushort*)(base + epi_b + 8192 * 2);

    hipLaunchKernelGGL(prep_kernel, dim3(B_CNT + 256 + 32), dim3(256), 0, stream,
                       x, T, W1, W2, xb16, epi, W1t, W2t, do_xb);
    if (do_xb) {
        hipLaunchKernelGGL((mlp_kernel<true>), dim3(GRID_MLP), dim3(512), 0, stream,
                           x, xb16, b1, b2, W3, b3, W1t, W2t, epi, (float*)d_out);
    } else {
        hipLaunchKernelGGL((mlp_kernel<false>), dim3(GRID_MLP), dim3(512), 0, stream,
                           x, xb16, b1, b2, W3, b3, W1t, W2t, epi, (float*)d_out);
    }
}

// Round 7
// 174.291 us; speedup vs baseline: 1.0605x; 1.0605x over previous
//
#include <hip/hip_runtime.h>
#include <stdint.h>

// Problem constants: B=2048, C=200, F=32, H=256. All tensors fp32 in/out.
// M = B*C = 409600 rows of 32 features, contiguous in x.
#define M_ROWS 409600
#define B_CNT  2048
#define C_CNT  200
#define N_TILES (M_ROWS / 64)    // 6400 tiles of 64 rows
#define GRID_MLP 512             // persistent blocks: 2 per CU

typedef __attribute__((ext_vector_type(8))) short bf16x8;   // 8 bf16 = 4 VGPRs
typedef __attribute__((ext_vector_type(4))) float f32x4;

// round-to-nearest-even f32 -> bf16 bits (scalar path, prep kernel)
__device__ __forceinline__ ushort f2bf(float f) {
    uint32_t u = __float_as_uint(f);
    u += 0x7fffu + ((u >> 16) & 1u);
    return (ushort)(u >> 16);
}

// packed RNE f32x2 -> bf16x2 (single HW instruction)
__device__ __forceinline__ uint32_t cvtpk_bf16(float lo, float hi) {
    uint32_t r;
    asm("v_cvt_pk_bf16_f32 %0, %1, %2" : "=v"(r) : "v"(lo), "v"(hi));
    return r;
}

__device__ __forceinline__ f32x4 mfma16(bf16x8 a, bf16x8 b, f32x4 c) {
    return __builtin_amdgcn_mfma_f32_16x16x32_bf16(a, b, c, 0, 0, 0);
}

__device__ __forceinline__ bf16x8 pack8(float4 a, float4 b) {
    bf16x8 r;
    r[0] = (short)f2bf(a.x); r[1] = (short)f2bf(a.y);
    r[2] = (short)f2bf(a.z); r[3] = (short)f2bf(a.w);
    r[4] = (short)f2bf(b.x); r[5] = (short)f2bf(b.y);
    r[6] = (short)f2bf(b.z); r[7] = (short)f2bf(b.w);
    return r;
}

// ---------------------------------------------------------------------------
// Prep kernel (unchanged, measured-good):
//   blocks [0,2048):   one coalesced pass over the x row: bf16 copy (xb16),
//                      sinflow/iinflow, fused epilogue operand
//                      epi[gm] = {S, P, Q, 0}:
//                        P = S + sinflow - outflow*S,  Q = I + iinflow - outflow*I
//   blocks [2048,2304): W2^T -> bf16
//   blocks [2304,2336): W1^T -> bf16
// ---------------------------------------------------------------------------
__global__ __launch_bounds__(256) void prep_kernel(
    const float* __restrict__ x, const float* __restrict__ T,
    const float* __restrict__ W1, const float* __restrict__ W2,
    ushort* __restrict__ xb16, float4* __restrict__ epi,
    ushort* __restrict__ W1t, ushort* __restrict__ W2t, int do_xb) {
    int blk = blockIdx.x, t = threadIdx.x;
    if (blk < B_CNT) {
        __shared__ float Sr[C_CNT], Ir[C_CNT];
        const float4* xr = (const float4*)(x + (size_t)blk * 6400);  // 1600 f4
        ushort4* xw = (ushort4*)(xb16 + (size_t)blk * 6400);
#pragma unroll
        for (int i = 0; i < 7; ++i) {
            int i4 = i * 256 + t;
            if (i4 < 1600) {
                float4 v = xr[i4];
                if (do_xb) {
                    ushort4 u;
                    u.x = f2bf(v.x); u.y = f2bf(v.y);
                    u.z = f2bf(v.z); u.w = f2bf(v.w);
                    xw[i4] = u;
                }
                if ((i4 & 7) == 0) {           // element i4*4 is feature 0 of c
                    int c = i4 >> 3;
                    Sr[c] = v.x; Ir[c] = v.y;
                }
            }
        }
        __syncthreads();
        if (t < C_CNT) {
            float as = 0.f, ai = 0.f;
            for (int cp = 0; cp < C_CNT; ++cp) {
                float tv = T[cp * C_CNT + t];        // coalesced over t, L2-hot
                as = fmaf(Sr[cp], tv, as);
                ai = fmaf(Ir[cp], tv, ai);
            }
            float S = Sr[t], I = Ir[t];
            float of = 1.0f - T[t * C_CNT + t];
            float4 e;
            e.x = S;
            e.y = S + as - of * S;   // P
            e.z = I + ai - of * I;   // Q
            e.w = 0.f;
            epi[(size_t)blk * C_CNT + t] = e;
        }
    } else if (blk < B_CNT + 256) {
        int n = blk - B_CNT;                          // one n2 row per block
        W2t[n * 256 + t] = f2bf(W2[t * 256 + n]);     // write coalesced
    } else {
        int idx = (blk - B_CNT - 256) * 256 + t;      // 0..8191
        int n = idx >> 5, k = idx & 31;
        W1t[idx] = f2bf(W1[k * 256 + n]);
    }
}

// ---------------------------------------------------------------------------
// Persistent fused MLP kernel — r5 structure (4 waves, 2 blocks/CU, one
// barrier/tile) with the GEMM1/pack phase SPLIT into two i1-chunks so the
// acc1 live range is 32 regs instead of 64. Register peaks:
//   GEMM1/pack : a2r 128 + acc1 32 + bx 16 + aw 8  ~ 184
//   GEMM2      : a2r 128 + acc2 64 + bh 16         ~ 215
// both under the 256/wave budget -> no scratch.
// Per iteration t:
//   [chunk c=0,1: aw(2) load | 8 MFMA GEMM1 | pack 32 cols -> h1s[buf]]
//   BARRIER | epilogue(t-1) [epi regs prefetched] | GEMM2(t) regs x LDS
//   | bx reload(t+1) (after the register peak) | epi prefetch(t) | GEMM3(t)
// ---------------------------------------------------------------------------
template <bool XB>
__global__ __launch_bounds__(256, 2) void mlp_kernel(
    const float* __restrict__ x,
    const ushort* __restrict__ xb16,
    const float* __restrict__ b1,
    const float* __restrict__ b2,
    const float* __restrict__ W3,
    const float* __restrict__ b3,
    const ushort* __restrict__ W1t,   // [256][32]  bf16, n1-major
    const ushort* __restrict__ W2t,   // [256][256] bf16, n2-major
    const float4* __restrict__ epi,   // {S, P, Q, 0} per row
    float* __restrict__ out) {
    constexpr int RS = 264;  // h1 row stride (ushorts): rows 16B-aligned
    __shared__ ushort h1s[2][64 * RS];       // 2 x 33792 B
    __shared__ float b1f[256], b2f[256], w3f[256];
    __shared__ float lamb2[2][4][64];        // parity double buffer

    const int tid  = threadIdx.x;
    const int w    = tid >> 6;
    const int lane = tid & 63;
    const int L    = lane & 15;
    const int q    = lane >> 4;

    b1f[tid] = b1[tid];
    b2f[tid] = b2[tid];
    w3f[tid] = W3[tid];
    const float b3v = b3[0];

    // ---- register-resident W2t slice (loaded once, reused every tile) ----
    bf16x8 a2r[4][8];                 // [i2][kc]
#pragma unroll
    for (int i2 = 0; i2 < 4; ++i2)
#pragma unroll
        for (int kc = 0; kc < 8; ++kc)
            a2r[i2][kc] =
                *(const bf16x8*)(W2t + (64 * w + i2 * 16 + L) * 256 + kc * 32 + q * 8);

    // W1t fragment byte-offset (32-bit, SGPR base); laundered per iteration
    uint32_t w1off = (uint32_t)(((64 * w + L) * 32 + q * 8) * sizeof(ushort));

    // ---- prologue: preload bx for the first tile ----
    int tile = blockIdx.x;
    bf16x8 bx[4];
#pragma unroll
    for (int i = 0; i < 4; ++i) {
        if (XB) {
            bx[i] = *(const bf16x8*)(xb16 + (size_t)(tile * 64 + i * 16 + L) * 32 + q * 8);
        } else {
            const float4* xr =
                (const float4*)(x + (size_t)(tile * 64 + i * 16 + L) * 32 + q * 8);
            bx[i] = pack8(xr[0], xr[1]);
        }
    }

    float eS = 0.f, eP = 0.f, eQ = 0.f;  // prefetched epilogue operands
    int ptile = -1;      // tile whose epilogue is pending
    int buf = 0, wp = 0;

    __syncthreads();     // b1f/b2f/w3f visible

    for (; tile < N_TILES; tile += GRID_MLP) {
        // ---- GEMM1+pack in TWO chunks: acc1 live range = 32 regs, not 64.
        asm volatile("" : "+v"(w1off));
        const char* w1p = (const char*)W1t + w1off;
#pragma unroll
        for (int c = 0; c < 2; ++c) {
            bf16x8 aw[2];
#pragma unroll
            for (int i = 0; i < 2; ++i)
                aw[i] = *(const bf16x8*)(w1p + (size_t)(c * 2 + i) * 1024);

            f32x4 acc1[2][4];
#pragma unroll
            for (int i1 = 0; i1 < 2; ++i1)
#pragma unroll
                for (int im = 0; im < 4; ++im)
                    acc1[i1][im] = mfma16(aw[i1], bx[im], (f32x4){0.f, 0.f, 0.f, 0.f});

            // pack these 32 n1-columns (bias+relu fp32, cvt_pk bf16) -> h1s[buf]
            // Safe pre-barrier: buf == buf(t-2); all waves passed barrier(t-1),
            // whose program order puts GEMM2(t-2) (last reader of buf) first.
#pragma unroll
            for (int i1 = 0; i1 < 2; ++i1) {
                int n1b = 64 * w + (c * 2 + i1) * 16 + q * 4;
                const float4 bv = *reinterpret_cast<const float4*>(&b1f[n1b]);
#pragma unroll
                for (int im = 0; im < 4; ++im) {
                    int m = im * 16 + L;
                    float v0 = fmaxf(acc1[i1][im][0] + bv.x, 0.f);
                    float v1 = fmaxf(acc1[i1][im][1] + bv.y, 0.f);
                    float v2 = fmaxf(acc1[i1][im][2] + bv.z, 0.f);
                    float v3 = fmaxf(acc1[i1][im][3] + bv.w, 0.f);
                    uint2 pk;
                    pk.x = cvtpk_bf16(v0, v1);
                    pk.y = cvtpk_bf16(v2, v3);
                    *reinterpret_cast<uint2*>(&h1s[buf][m * RS + n1b]) = pk;
                }
            }
        }

        __syncthreads();   // THE barrier: h1s[buf] ready; lamb2[wp^1] visible

        // ---- pipelined epilogue for tile t-1 (overlaps other waves' GEMM2)
        if (ptile >= 0 && tid < 64) {
            int gm = ptile * 64 + tid;
            float lam = lamb2[wp ^ 1][0][tid] + lamb2[wp ^ 1][1][tid] +
                        lamb2[wp ^ 1][2][tid] + lamb2[wp ^ 1][3][tid] + b3v;
            float2 o;
            o.x = eP - lam * eS;
            o.y = eQ + lam * eS;
            ((float2*)out)[gm] = o;   // coalesced 8B store
        }

        // ---- GEMM2 (K=256, 8 k-chunks): A from registers, B from LDS ----
        f32x4 acc2[4][4];
#pragma unroll
        for (int i2 = 0; i2 < 4; ++i2)
#pragma unroll
            for (int im = 0; im < 4; ++im) acc2[i2][im] = (f32x4){0.f, 0.f, 0.f, 0.f};

#pragma unroll
        for (int kc = 0; kc < 8; ++kc) {
            bf16x8 bh[4];
#pragma unroll
            for (int im = 0; im < 4; ++im) {
                int m = im * 16 + L;
                bh[im] = *(const bf16x8*)(&h1s[buf][m * RS + kc * 32 + q * 8]);
            }
#pragma unroll
            for (int i2 = 0; i2 < 4; ++i2)
#pragma unroll
                for (int im = 0; im < 4; ++im)
                    acc2[i2][im] = mfma16(a2r[i2][kc], bh[im], acc2[i2][im]);
        }

        // ---- bx reload for next tile: AFTER the GEMM2 register peak ----
        {
            int tn = tile + GRID_MLP;
            if (tn >= N_TILES) tn = tile;   // harmless dummy reload on last iter
            const size_t mn0 = (size_t)tn * 64;
#pragma unroll
            for (int i = 0; i < 4; ++i) {
                if (XB) {
                    bx[i] = *(const bf16x8*)(xb16 + (mn0 + i * 16 + L) * 32 + q * 8);
                } else {
                    const float4* xr =
                        (const float4*)(x + (mn0 + i * 16 + L) * 32 + q * 8);
                    bx[i] = pack8(xr[0], xr[1]);
                }
            }
        }

        // ---- prefetch epilogue operands for THIS tile (consumed next iter)
        if (tid < 64) {
            float4 e = epi[(size_t)tile * 64 + tid];
            eS = e.x; eP = e.y; eQ = e.z;
        }

        // ---- GEMM3: lamb[m] = sum_n2 relu(h2 + b2) * W3 (fp32, exact) ----
        float part[4] = {0.f, 0.f, 0.f, 0.f};
#pragma unroll
        for (int i2 = 0; i2 < 4; ++i2) {
            int n2b = 64 * w + i2 * 16 + q * 4;
            const float4 b2v = *reinterpret_cast<const float4*>(&b2f[n2b]);
            const float4 w3v = *reinterpret_cast<const float4*>(&w3f[n2b]);
#pragma unroll
            for (int im = 0; im < 4; ++im) {
                float h0 = fmaxf(acc2[i2][im][0] + b2v.x, 0.f);
                float h1 = fmaxf(acc2[i2][im][1] + b2v.y, 0.f);
                float h2 = fmaxf(acc2[i2][im][2] + b2v.z, 0.f);
                float h3 = fmaxf(acc2[i2][im][3] + b2v.w, 0.f);
                part[im] = fmaf(h0, w3v.x, part[im]);
                part[im] = fmaf(h1, w3v.y, part[im]);
                part[im] = fmaf(h2, w3v.z, part[im]);
                part[im] = fmaf(h3, w3v.w, part[im]);
            }
        }

#pragma unroll
        for (int im = 0; im < 4; ++im) {
            float pp = part[im];
            pp += __shfl_xor(pp, 16);
            pp += __shfl_xor(pp, 32);
            if (q == 0) lamb2[wp][w][im * 16 + L] = pp;
        }
        // lamb2[wp] is consumed only after the NEXT barrier.

        ptile = tile;
        buf ^= 1;
        wp ^= 1;
    }

    // ---- drain: epilogue for the final tile ----
    __syncthreads();
    if (ptile >= 0 && tid < 64) {
        int gm = ptile * 64 + tid;
        float lam = lamb2[wp ^ 1][0][tid] + lamb2[wp ^ 1][1][tid] +
                    lamb2[wp ^ 1][2][tid] + lamb2[wp ^ 1][3][tid] + b3v;
        float2 o;
        o.x = eP - lam * eS;
        o.y = eQ + lam * eS;
        ((float2*)out)[gm] = o;
    }
}

// ---------------------------------------------------------------------------
extern "C" void kernel_launch(void* const* d_in, const int* in_sizes, int n_in,
                              void* d_out, int out_size, void* d_ws, size_t ws_size,
                              hipStream_t stream) {
    const float* x  = (const float*)d_in[0];
    const float* T  = (const float*)d_in[1];
    const float* W1 = (const float*)d_in[2];
    const float* b1 = (const float*)d_in[3];
    const float* W2 = (const float*)d_in[4];
    const float* b2 = (const float*)d_in[5];
    const float* W3 = (const float*)d_in[6];
    const float* b3 = (const float*)d_in[7];

    // ws layout: [xb16 (opt, 26.2 MB)] epi (6.55 MB) W1t (16KB) W2t (128KB)
    const size_t xb_bytes = (size_t)M_ROWS * 32 * 2;
    const size_t epi_b    = (size_t)M_ROWS * 16;
    const size_t small    = epi_b + 8192 * 2 + 65536 * 2;
    const int    do_xb    = (ws_size >= xb_bytes + small) ? 1 : 0;

    char* ws = (char*)d_ws;
    ushort* xb16 = (ushort*)ws;
    char* base = ws + (do_xb ? xb_bytes : 0);
    float4* epi  = (float4*)(base);
    ushort* W1t  = (ushort*)(base + epi_b);
    ushort* W2t  = (ushort*)(base + epi_b + 8192 * 2);

    hipLaunchKernelGGL(prep_kernel, dim3(B_CNT + 256 + 32), dim3(256), 0, stream,
                       x, T, W1, W2, xb16, epi, W1t, W2t, do_xb);
    if (do_xb) {
        hipLaunchKernelGGL((mlp_kernel<true>), dim3(GRID_MLP), dim3(256), 0, stream,
                           x, xb16, b1, b2, W3, b3, W1t, W2t, epi, (float*)d_out);
    } else {
        hipLaunchKernelGGL((mlp_kernel<false>), dim3(GRID_MLP), dim3(256), 0, stream,
                           x, xb16, b1, b2, W3, b3, W1t, W2t, epi, (float*)d_out);
    }
}